// Round 1
// baseline (458.576 us; speedup 1.0000x reference)
//
#include <hip/hip_runtime.h>

// EmittanceModule: S=32768 samples, d_tune=8, n_steps=16, H=256.
// ys[s,j] = sum_h tanh( x[s]·W1[s,:8,h] + k_j·W1[s,8,h] + b1[s,h] ) * w2[s,h]
// Xc = ys @ pinv(A)^T ; sigs = Xc @ M^T ; out = sum_s sigs0*sigs2 - sigs1^2
// Fold G = M @ pinv(A)  (3x16, sample-independent) -> per-sample result is a
// quadratic form in 3 wave-reduced accumulators.

#define NSTEPS 16
#define NSAMP  32768

// L=0.1, D=1.0:
//   M = [[100,0,0],[-100,5,0],[100,-10,1]]
__global__ void setup_kg(const float* __restrict__ Xm, float4* __restrict__ kg) {
    if (threadIdx.x == 0 && blockIdx.x == 0) {
        double k[NSTEPS];
        double S1 = 0, S2 = 0, S3 = 0, S4 = 0;
        for (int j = 0; j < NSTEPS; ++j) {
            double kj = (double)Xm[j];
            k[j] = kj;
            double k2 = kj * kj;
            S1 += kj; S2 += k2; S3 += k2 * kj; S4 += k2 * k2;
        }
        double S0 = (double)NSTEPS;
        // AtA = [[S4,S3,S2],[S3,S2,S1],[S2,S1,S0]] (symmetric), invert via adjugate
        double a = S4, b = S3, c = S2, d = S2, e = S1, f = S0;
        double A00 = d * f - e * e;
        double A01 = -(b * f - c * e);
        double A02 = b * e - c * d;
        double det = a * A00 + b * A01 + c * A02;
        double A11 = a * f - c * c;
        double A12 = -(a * e - b * c);
        double A22 = a * d - b * b;
        double i00 = A00 / det, i01 = A01 / det, i02 = A02 / det;
        double i11 = A11 / det, i12 = A12 / det, i22 = A22 / det;
        for (int j = 0; j < NSTEPS; ++j) {
            double kj = k[j], k2 = kj * kj;
            // P = inv(AtA) @ A^T, column j
            double P0 = i00 * k2 + i01 * kj + i02;
            double P1 = i01 * k2 + i11 * kj + i12;
            double P2 = i02 * k2 + i12 * kj + i22;
            // G = M @ P
            double G0 = 100.0 * P0;
            double G1 = -100.0 * P0 + 5.0 * P1;
            double G2 = 100.0 * P0 - 10.0 * P1 + 1.0 * P2;
            kg[j] = make_float4((float)kj, (float)G0, (float)G1, (float)G2);
        }
    }
}

// tanh(x) = 1 - 2/(exp(2x)+1); exp(2x) = exp2(x * 2*log2(e))
__device__ __forceinline__ float fast_tanh(float v) {
    float e = __builtin_amdgcn_exp2f(v * 2.8853900817779268f);
    return 1.0f - 2.0f * __builtin_amdgcn_rcpf(e + 1.0f);
}

__global__ __launch_bounds__(256) void emit_main(
    const float* __restrict__ x,
    const float* __restrict__ W1,
    const float* __restrict__ b1,
    const float* __restrict__ w2,
    const float4* __restrict__ kg,
    float* __restrict__ out)
{
    const int tid  = threadIdx.x;
    const int lane = tid & 63;
    const int wid  = tid >> 6;
    const int s    = blockIdx.x * 4 + wid;   // one wave per sample

    // Each lane owns 4 consecutive hidden units: h = lane*4 .. lane*4+3
    const float4* W1v = (const float4*)(W1 + (size_t)s * (9 * 256));
    float4 w1r[9];
#pragma unroll
    for (int d = 0; d < 9; ++d) w1r[d] = W1v[d * 64 + lane];
    const float4 bv = ((const float4*)(b1 + (size_t)s * 256))[lane];
    const float4 wv = ((const float4*)(w2 + (size_t)s * 256))[lane];
    const float* xs = x + (size_t)s * 8;

    // base = b1 + sum_d x[d] * W1[d, h]
    float base0 = bv.x, base1 = bv.y, base2 = bv.z, base3 = bv.w;
#pragma unroll
    for (int d = 0; d < 8; ++d) {
        const float xd = xs[d];
        base0 = fmaf(xd, w1r[d].x, base0);
        base1 = fmaf(xd, w1r[d].y, base1);
        base2 = fmaf(xd, w1r[d].z, base2);
        base3 = fmaf(xd, w1r[d].w, base3);
    }

    float sig0 = 0.0f, sig1 = 0.0f, sig2 = 0.0f;
#pragma unroll
    for (int j = 0; j < NSTEPS; ++j) {
        const float4 g = kg[j];           // {k_j, G0j, G1j, G2j} (uniform, L2-hot)
        const float kj = g.x;
        float t0 = fast_tanh(fmaf(kj, w1r[8].x, base0)) * wv.x;
        float t1 = fast_tanh(fmaf(kj, w1r[8].y, base1)) * wv.y;
        float t2 = fast_tanh(fmaf(kj, w1r[8].z, base2)) * wv.z;
        float t3 = fast_tanh(fmaf(kj, w1r[8].w, base3)) * wv.w;
        const float tw = (t0 + t1) + (t2 + t3);   // partial ys[s,j]
        sig0 = fmaf(g.y, tw, sig0);
        sig1 = fmaf(g.z, tw, sig1);
        sig2 = fmaf(g.w, tw, sig2);
    }

    // wave64 reduce the 3 sigma partials
#pragma unroll
    for (int off = 32; off > 0; off >>= 1) {
        sig0 += __shfl_xor(sig0, off, 64);
        sig1 += __shfl_xor(sig1, off, 64);
        sig2 += __shfl_xor(sig2, off, 64);
    }

    __shared__ float part[4];
    if (lane == 0) part[wid] = fmaf(sig0, sig2, -(sig1 * sig1));
    __syncthreads();
    if (tid == 0) {
        const float tot = (part[0] + part[1]) + (part[2] + part[3]);
        atomicAdd(out, tot);
    }
}

extern "C" void kernel_launch(void* const* d_in, const int* in_sizes, int n_in,
                              void* d_out, int out_size, void* d_ws, size_t ws_size,
                              hipStream_t stream) {
    const float* x  = (const float*)d_in[0];
    const float* Xm = (const float*)d_in[1];
    const float* W1 = (const float*)d_in[2];
    const float* b1 = (const float*)d_in[3];
    const float* w2 = (const float*)d_in[4];
    float* out = (float*)d_out;
    float4* kg = (float4*)d_ws;

    hipMemsetAsync(out, 0, sizeof(float), stream);
    setup_kg<<<1, 1, 0, stream>>>(Xm, kg);
    emit_main<<<NSAMP / 4, 256, 0, stream>>>(x, W1, b1, w2, kg, out);
}

// Round 3
// 443.963 us; speedup vs baseline: 1.0329x; 1.0329x over previous
//
#include <hip/hip_runtime.h>

// EmittanceModule: S=32768 samples, d_tune=8, n_steps=16, H=256.
// ys[s,j] = sum_h tanh( x[s]·W1[s,:8,h] + k_j·W1[s,8,h] + b1[s,h] ) * w2[s,h]
// Xc = ys @ pinv(A)^T ; sigs = Xc @ M^T ; out = sum_s sigs0*sigs2 - sigs1^2
// G = M @ pinv(A) (3x16, sample-independent) folded once in setup_kg; the
// per-sample result is a quadratic form in 3 wave-reduced accumulators.
// Epilogue: per-block partials in d_ws + one tree-reduce block (no same-address
// atomic storm, no d_out memset needed).

#define NSTEPS 16
#define NSAMP  32768
#define NBLOCKS (NSAMP / 4)

// L=0.1, D=1.0:  M = [[100,0,0],[-100,5,0],[100,-10,1]]
__global__ void setup_kg(const float* __restrict__ Xm, float4* __restrict__ kg) {
    if (threadIdx.x == 0 && blockIdx.x == 0) {
        double k[NSTEPS];
        double S1 = 0, S2 = 0, S3 = 0, S4 = 0;
        for (int j = 0; j < NSTEPS; ++j) {
            double kj = (double)Xm[j];
            k[j] = kj;
            double k2 = kj * kj;
            S1 += kj; S2 += k2; S3 += k2 * kj; S4 += k2 * k2;
        }
        double S0 = (double)NSTEPS;
        // AtA = [[S4,S3,S2],[S3,S2,S1],[S2,S1,S0]] (symmetric); invert via adjugate
        double a = S4, b = S3, c = S2, d = S2, e = S1, f = S0;
        double A00 = d * f - e * e;
        double A01 = -(b * f - c * e);
        double A02 = b * e - c * d;
        double det = a * A00 + b * A01 + c * A02;
        double A11 = a * f - c * c;
        double A12 = -(a * e - b * c);
        double A22 = a * d - b * b;
        double i00 = A00 / det, i01 = A01 / det, i02 = A02 / det;
        double i11 = A11 / det, i12 = A12 / det, i22 = A22 / det;
        for (int j = 0; j < NSTEPS; ++j) {
            double kj = k[j], k2 = kj * kj;
            // P = inv(AtA) @ A^T, column j
            double P0 = i00 * k2 + i01 * kj + i02;
            double P1 = i01 * k2 + i11 * kj + i12;
            double P2 = i02 * k2 + i12 * kj + i22;
            // G = M @ P
            double G0 = 100.0 * P0;
            double G1 = -100.0 * P0 + 5.0 * P1;
            double G2 = 100.0 * P0 - 10.0 * P1 + 1.0 * P2;
            kg[j] = make_float4((float)kj, (float)G0, (float)G1, (float)G2);
        }
    }
}

// tanh(x) = 1 - 2/(exp(2x)+1); exp(2x) = exp2(x * 2*log2(e))
__device__ __forceinline__ float fast_tanh(float v) {
    float e = __builtin_amdgcn_exp2f(v * 2.8853900817779268f);
    return 1.0f - 2.0f * __builtin_amdgcn_rcpf(e + 1.0f);
}

__global__ __launch_bounds__(256) void emit_main(
    const float* __restrict__ x,
    const float* __restrict__ W1,
    const float* __restrict__ b1,
    const float* __restrict__ w2,
    const float4* __restrict__ kg,
    float* __restrict__ partials)
{
    const int tid  = threadIdx.x;
    const int lane = tid & 63;
    const int wid  = tid >> 6;
    const int s    = blockIdx.x * 4 + wid;   // one wave per sample

    // Each lane owns 4 consecutive hidden units: h = lane*4 .. lane*4+3
    const float4* W1v = (const float4*)(W1 + (size_t)s * (9 * 256));
    float4 w1r[9];
#pragma unroll
    for (int d = 0; d < 9; ++d) w1r[d] = W1v[d * 64 + lane];
    const float4 bv = ((const float4*)(b1 + (size_t)s * 256))[lane];
    const float4 wv = ((const float4*)(w2 + (size_t)s * 256))[lane];
    const float* xs = x + (size_t)s * 8;

    // base = b1 + sum_d x[d] * W1[d, h]
    float base0 = bv.x, base1 = bv.y, base2 = bv.z, base3 = bv.w;
#pragma unroll
    for (int d = 0; d < 8; ++d) {
        const float xd = xs[d];
        base0 = fmaf(xd, w1r[d].x, base0);
        base1 = fmaf(xd, w1r[d].y, base1);
        base2 = fmaf(xd, w1r[d].z, base2);
        base3 = fmaf(xd, w1r[d].w, base3);
    }

    float sig0 = 0.0f, sig1 = 0.0f, sig2 = 0.0f;
#pragma unroll
    for (int j = 0; j < NSTEPS; ++j) {
        const float4 g = kg[j];           // {k_j, G0j, G1j, G2j} (uniform, L2-hot)
        const float kj = g.x;
        float t0 = fast_tanh(fmaf(kj, w1r[8].x, base0)) * wv.x;
        float t1 = fast_tanh(fmaf(kj, w1r[8].y, base1)) * wv.y;
        float t2 = fast_tanh(fmaf(kj, w1r[8].z, base2)) * wv.z;
        float t3 = fast_tanh(fmaf(kj, w1r[8].w, base3)) * wv.w;
        const float tw = (t0 + t1) + (t2 + t3);   // partial ys[s,j]
        sig0 = fmaf(g.y, tw, sig0);
        sig1 = fmaf(g.z, tw, sig1);
        sig2 = fmaf(g.w, tw, sig2);
    }

    // wave64 reduce the 3 sigma partials
#pragma unroll
    for (int off = 32; off > 0; off >>= 1) {
        sig0 += __shfl_xor(sig0, off, 64);
        sig1 += __shfl_xor(sig1, off, 64);
        sig2 += __shfl_xor(sig2, off, 64);
    }

    __shared__ float part[4];
    if (lane == 0) part[wid] = fmaf(sig0, sig2, -(sig1 * sig1));
    __syncthreads();
    if (tid == 0)
        partials[blockIdx.x] = (part[0] + part[1]) + (part[2] + part[3]);
}

// Single-block tree reduce of the 8192 per-block partials -> out[0].
__global__ __launch_bounds__(1024) void final_reduce(
    const float* __restrict__ partials, float* __restrict__ out)
{
    const int tid  = threadIdx.x;
    const int lane = tid & 63;
    const int wid  = tid >> 6;

    const float4* p4 = (const float4*)partials;   // 2048 float4s
    float4 a = p4[tid];
    float4 b = p4[tid + 1024];
    float v = ((a.x + a.y) + (a.z + a.w)) + ((b.x + b.y) + (b.z + b.w));
#pragma unroll
    for (int off = 32; off > 0; off >>= 1) v += __shfl_xor(v, off, 64);

    __shared__ float wsum[16];
    if (lane == 0) wsum[wid] = v;
    __syncthreads();
    if (wid == 0) {
        float t = (lane < 16) ? wsum[lane] : 0.0f;
#pragma unroll
        for (int off = 8; off > 0; off >>= 1) t += __shfl_xor(t, off, 64);
        if (lane == 0) out[0] = t;
    }
}

extern "C" void kernel_launch(void* const* d_in, const int* in_sizes, int n_in,
                              void* d_out, int out_size, void* d_ws, size_t ws_size,
                              hipStream_t stream) {
    const float* x  = (const float*)d_in[0];
    const float* Xm = (const float*)d_in[1];
    const float* W1 = (const float*)d_in[2];
    const float* b1 = (const float*)d_in[3];
    const float* w2 = (const float*)d_in[4];
    float* out = (float*)d_out;

    float4* kg = (float4*)d_ws;                       // 16 * 16 B
    float* partials = (float*)d_ws + 64;              // 8192 floats, 16B-aligned

    setup_kg<<<1, 1, 0, stream>>>(Xm, kg);
    emit_main<<<NBLOCKS, 256, 0, stream>>>(x, W1, b1, w2, kg, partials);
    final_reduce<<<1, 1024, 0, stream>>>(partials, out);
}